// Round 5
// baseline (826.426 us; speedup 1.0000x reference)
//
#include <hip/hip_runtime.h>

#define NSEQ 256
#define NRES 1024
#define CM   256
#define CC   32
#define CZ   128
#define EPS  1e-5f
#define SROW (NRES * CM)   // stride between s-rows of x for fixed r
#define MCH  16            // m-chunk size (floats)
#define XPAD 20            // row stride: 20*i mod 32 hits 8 distinct 4-bank groups
#define CHF  (NSEQ * XPAD) // 5120 floats per residue chunk buffer

typedef float f4v __attribute__((ext_vector_type(4)));

// ===================== Kernel S: precompute wt[m][c], K1, K2 =====================
__global__ void opm_setup(const float* __restrict__ nw,
                          const float* __restrict__ nb,
                          const float* __restrict__ w_ab,
                          const float* __restrict__ b_ab,
                          float* __restrict__ wt_g,
                          float* __restrict__ k12)
{
    __shared__ float wls[CM * CC];
    const int t = threadIdx.x;          // 256 threads, t == m
    const float nwm = nw[t];
    #pragma unroll
    for (int c = 0; c < CC; ++c)
        wls[t * CC + c] = nwm * w_ab[c * CM + t];
    __syncthreads();
    for (int i = t; i < CM * CC; i += 256) wt_g[i] = wls[i];
    if (t < CC) {
        float k1 = 0.f, k2 = 0.f;
        for (int m = 0; m < CM; ++m) {
            k1 += wls[m * CC + t];
            k2 = fmaf(nb[m], w_ab[t * CM + m], k2);
        }
        k12[t]      = k1;
        k12[CC + t] = k2 + b_ab[t];
    }
}

// ===================== Kernel A: compute pre[r][z], TWO residues per block =====================
// 512 blocks (full residency at 2/CU), 256 threads = 4 waves.
// Threads 0..127 -> residue r0, 128..255 -> r0+1; both share wt (32 KB).
// Per-residue G tile: 128 threads x (8 rows x 8 cols); reads/FMA = 1/16+1/32... 
//   = 0.0625 b128/FMA (was 0.094): 16 b128 per 256 FMAs per mm-step.
// LDS (72 KB -> 2 blocks/CU):
//   wt[8192]   32 KB : weights during G; a[s][c] for residue 0 after P2.
//   xa[10240]  40 KB : per-res chunk buffers [res*5120 .. +5120) during G;
//                      a (res 1) at [0..8191] after P2;
//                      stat mu/rstd at [8192..10239] (post-G, pre-P3);
//                      P3 partials/o at [8192..10239] (post-P2).
// Bank audits (per wave): x-read rows rg+32j, stride 20 -> 16 rows over 8
//   4-bank groups = 2-way (free, m136); wt-read 4 distinct f4 slots
//   {0,8,16,24}+{4,12,20,28} (free); P3 = round-3 8x8 XOR-swizzle (free).
__launch_bounds__(256, 2)
__global__ void opm_compute(const float* __restrict__ msa,
                            const float* __restrict__ wt_g,
                            const float* __restrict__ k12,
                            const float* __restrict__ w_out,
                            const float* __restrict__ b_out,
                            float* __restrict__ pre_out)
{
    __shared__ float wt[CM * CC];        // 32 KB
    __shared__ float xa[2 * CHF];        // 40 KB

    const int tid = threadIdx.x;
    const int r0  = blockIdx.x << 1;
    const int res = tid >> 7;            // which residue this thread serves
    const int t   = tid & 127;

    // staging identity (per residue: 128 stagers)
    const int sc4 = t & 3;               // f4 slot within 16-float row window
    const int sg  = t >> 2;              // 0..31; rows sg+32k, k=0..7
    // compute identity (per residue)
    const int cg  = t & 3;               // col group: cols c0..c0+7
    const int rg  = t >> 2;              // 0..31; rows rg+32j, j=0..7
    const int c0  = cg << 3;

    float* chunk = xa + res * CHF;
    float* stat  = xa + 2 * CHF - 2048;  // [8192..10239]
    const float* xr = msa + (size_t)(r0 + res) * CM + (sc4 << 2);

    // stage wt[m][c] from global (visible at first in-loop barrier pair)
    #pragma unroll
    for (int k = 0; k < 8; ++k) {
        const int i = (tid + (k << 8)) << 2;
        *(float4*)&wt[i] = *(const float4*)&wt_g[i];
    }

    float G[8][8];
    #pragma unroll
    for (int j = 0; j < 8; ++j)
        #pragma unroll
        for (int c = 0; c < 8; ++c) G[j][c] = 0.f;
    float psum[8], pssq[8];
    #pragma unroll
    for (int k = 0; k < 8; ++k) { psum[k] = 0.f; pssq[k] = 0.f; }

    // prologue: prefetch chunk 0 (each thread: 8 rows x 16 B)
    float4 pf[8];
    #pragma unroll
    for (int k = 0; k < 8; ++k)
        pf[k] = *(const float4*)(xr + (size_t)(sg + (k << 5)) * SROW);

    for (int mb = 0; mb < CM; mb += MCH) {
        __syncthreads();   // previous chunk's readers done
        #pragma unroll
        for (int k = 0; k < 8; ++k) {
            *(float4*)&chunk[(sg + (k << 5)) * XPAD + (sc4 << 2)] = pf[k];
            psum[k] += (pf[k].x + pf[k].y) + (pf[k].z + pf[k].w);
            pssq[k]  = fmaf(pf[k].x, pf[k].x, fmaf(pf[k].y, pf[k].y,
                       fmaf(pf[k].z, pf[k].z, fmaf(pf[k].w, pf[k].w, pssq[k]))));
        }
        __syncthreads();   // chunk (and, first time, wt) visible
        if (mb + MCH < CM) {
            #pragma unroll
            for (int k = 0; k < 8; ++k)
                pf[k] = *(const float4*)(xr + (size_t)(sg + (k << 5)) * SROW + (mb + MCH));
        }
        #pragma unroll
        for (int mm = 0; mm < MCH; mm += 4) {
            float4 xv[8];
            #pragma unroll
            for (int j = 0; j < 8; ++j)
                xv[j] = *(const float4*)&chunk[(rg + (j << 5)) * XPAD + mm];
            #pragma unroll
            for (int q = 0; q < 4; ++q) {
                const float4 wa = *(const float4*)&wt[(mb + mm + q) * CC + c0];
                const float4 wb = *(const float4*)&wt[(mb + mm + q) * CC + c0 + 4];
                #pragma unroll
                for (int j = 0; j < 8; ++j) {
                    const float xq = (q == 0) ? xv[j].x : (q == 1) ? xv[j].y
                                   : (q == 2) ? xv[j].z : xv[j].w;
                    G[j][0] = fmaf(xq, wa.x, G[j][0]);
                    G[j][1] = fmaf(xq, wa.y, G[j][1]);
                    G[j][2] = fmaf(xq, wa.z, G[j][2]);
                    G[j][3] = fmaf(xq, wa.w, G[j][3]);
                    G[j][4] = fmaf(xq, wb.x, G[j][4]);
                    G[j][5] = fmaf(xq, wb.y, G[j][5]);
                    G[j][6] = fmaf(xq, wb.z, G[j][6]);
                    G[j][7] = fmaf(xq, wb.w, G[j][7]);
                }
            }
        }
    }
    __syncthreads();   // (A) all chunk + wt reads done; stat region (overlaps res1 chunk) safe

    // ---- stats: reduce over the 4 sc4-lanes, publish mu/rstd ----
    #pragma unroll
    for (int k = 0; k < 8; ++k) {
        float s1 = psum[k], s2 = pssq[k];
        s1 += __shfl_xor(s1, 1); s1 += __shfl_xor(s1, 2);
        s2 += __shfl_xor(s2, 1); s2 += __shfl_xor(s2, 2);
        if (sc4 == 0) {
            const int s = sg + (k << 5);
            const float mu  = s1 * (1.f / CM);
            const float var = s2 * (1.f / CM) - mu * mu;
            stat[(res << 9) + s]       = mu;
            stat[(res << 9) + 256 + s] = 1.f / sqrtf(var + EPS);
        }
    }
    __syncthreads();   // (B) mu/rstd visible

    // ---------------- P2: finalize a -> per-res region, XOR-swizzled f4 slots ----------------
    float* aB = res ? xa : wt;           // a[s][c] base for this thread's residue
    {
        const float4 k1a = *(const float4*)&k12[c0];
        const float4 k1b = *(const float4*)&k12[c0 + 4];
        const float4 k2a = *(const float4*)&k12[CC + c0];
        const float4 k2b = *(const float4*)&k12[CC + c0 + 4];
        #pragma unroll
        for (int j = 0; j < 8; ++j) {
            const int s = rg + (j << 5);
            const float mu   = stat[(res << 9) + s];
            const float rstd = stat[(res << 9) + 256 + s];
            float4 va, vb;
            va.x = fmaf(rstd, G[j][0] - mu * k1a.x, k2a.x);
            va.y = fmaf(rstd, G[j][1] - mu * k1a.y, k2a.y);
            va.z = fmaf(rstd, G[j][2] - mu * k1a.z, k2a.z);
            va.w = fmaf(rstd, G[j][3] - mu * k1a.w, k2a.w);
            vb.x = fmaf(rstd, G[j][4] - mu * k1b.x, k2b.x);
            vb.y = fmaf(rstd, G[j][5] - mu * k1b.y, k2b.y);
            vb.z = fmaf(rstd, G[j][6] - mu * k1b.z, k2b.z);
            vb.w = fmaf(rstd, G[j][7] - mu * k1b.w, k2b.w);
            const int sw = s & 7;
            *(float4*)&aB[s * CC + ((((cg << 1)    ) ^ sw) << 2)] = va;
            *(float4*)&aB[s * CC + ((((cg << 1) | 1) ^ sw) << 2)] = vb;
        }
    }
    __syncthreads();   // (C) a complete; mu reads done (partials may overwrite stat)

    // ---------------- P3: o = A^T A / NSEQ, split-K(2) x 4x4 tiles per residue ----------------
    const int h  = (t >> 6) & 1;         // s-half
    const int xs = (t >> 3) & 7;         // row f4-slot
    const int ys = t & 7;                // col f4-slot
    float4 pr0 = {0,0,0,0}, pr1 = {0,0,0,0}, pr2 = {0,0,0,0}, pr3 = {0,0,0,0};
    #pragma unroll 4
    for (int si = 0; si < 128; ++si) {
        const int s  = (h << 7) + si;
        const int sw = s & 7;
        const float4 ax = *(const float4*)&aB[s * CC + ((xs ^ sw) << 2)];
        const float4 ay = *(const float4*)&aB[s * CC + ((ys ^ sw) << 2)];
        pr0.x = fmaf(ax.x, ay.x, pr0.x); pr0.y = fmaf(ax.x, ay.y, pr0.y);
        pr0.z = fmaf(ax.x, ay.z, pr0.z); pr0.w = fmaf(ax.x, ay.w, pr0.w);
        pr1.x = fmaf(ax.y, ay.x, pr1.x); pr1.y = fmaf(ax.y, ay.y, pr1.y);
        pr1.z = fmaf(ax.y, ay.z, pr1.z); pr1.w = fmaf(ax.y, ay.w, pr1.w);
        pr2.x = fmaf(ax.z, ay.x, pr2.x); pr2.y = fmaf(ax.z, ay.y, pr2.y);
        pr2.z = fmaf(ax.z, ay.z, pr2.z); pr2.w = fmaf(ax.z, ay.w, pr2.w);
        pr3.x = fmaf(ax.w, ay.x, pr3.x); pr3.y = fmaf(ax.w, ay.y, pr3.y);
        pr3.z = fmaf(ax.w, ay.z, pr3.z); pr3.w = fmaf(ax.w, ay.w, pr3.w);
    }
    float* pb = &stat[(res << 10) + ((xs << 2) * CC) + (ys << 2)];
    if (h) {   // half-1 partial into stat region (mu dead; a region untouched)
        *(float4*)&pb[0 * CC] = pr0;
        *(float4*)&pb[1 * CC] = pr1;
        *(float4*)&pb[2 * CC] = pr2;
        *(float4*)&pb[3 * CC] = pr3;
    }
    __syncthreads();   // (D) partials visible
    if (!h) {  // half-0: o = (reg + partial) / NSEQ, written in place
        const float inv_s = 1.f / NSEQ;
        float4 q0 = *(const float4*)&pb[0 * CC];
        float4 q1 = *(const float4*)&pb[1 * CC];
        float4 q2 = *(const float4*)&pb[2 * CC];
        float4 q3 = *(const float4*)&pb[3 * CC];
        q0.x = (q0.x + pr0.x) * inv_s; q0.y = (q0.y + pr0.y) * inv_s;
        q0.z = (q0.z + pr0.z) * inv_s; q0.w = (q0.w + pr0.w) * inv_s;
        q1.x = (q1.x + pr1.x) * inv_s; q1.y = (q1.y + pr1.y) * inv_s;
        q1.z = (q1.z + pr1.z) * inv_s; q1.w = (q1.w + pr1.w) * inv_s;
        q2.x = (q2.x + pr2.x) * inv_s; q2.y = (q2.y + pr2.y) * inv_s;
        q2.z = (q2.z + pr2.z) * inv_s; q2.w = (q2.w + pr2.w) * inv_s;
        q3.x = (q3.x + pr3.x) * inv_s; q3.y = (q3.y + pr3.y) * inv_s;
        q3.z = (q3.z + pr3.z) * inv_s; q3.w = (q3.w + pr3.w) * inv_s;
        *(float4*)&pb[0 * CC] = q0;
        *(float4*)&pb[1 * CC] = q1;
        *(float4*)&pb[2 * CC] = q2;
        *(float4*)&pb[3 * CC] = q3;
    }
    __syncthreads();   // (E) o visible

    // ---------------- P4: pre[z] = o . w_out[z] + b_out[z] (1 thread per (res,z)) ----------------
    {
        const int z = t;                           // 0..127
        const float* wrow = w_out + (size_t)z * (CC * CC);
        const float* op   = &stat[res << 10];
        float po = 0.f;
        #pragma unroll 8
        for (int k = 0; k < CC * CC; k += 4) {
            const float4 o4 = *(const float4*)&op[k];
            const float4 w4 = *(const float4*)&wrow[k];
            po = fmaf(o4.x, w4.x, fmaf(o4.y, w4.y, fmaf(o4.z, w4.z, fmaf(o4.w, w4.w, po))));
        }
        pre_out[(size_t)(r0 + res) * CZ + z] = po + b_out[z];
    }
}

// ===================== Kernel B: broadcast pre over 1024 rows =====================
__launch_bounds__(256, 8)
__global__ void opm_bcast(const float* __restrict__ pre,
                          float* __restrict__ out)
{
    const int bid = blockIdx.x;
    const int r   = bid >> 3;                 // 0..1023
    const int jb  = bid & 7;                  // 128-row slab within the r-plane
    const int z4  = threadIdx.x & 31;         // which float4 of the 128-float row
    const int jo  = threadIdx.x >> 5;         // 0..7

    const f4v pv = *((const f4v*)(pre + (size_t)r * CZ) + z4);
    f4v* outp = (f4v*)out + ((size_t)r * NRES + (size_t)jb * 128) * (CZ / 4);
    for (int j0 = 0; j0 < 128; j0 += 8)
        __builtin_nontemporal_store(pv, &outp[(size_t)(j0 + jo) * (CZ / 4) + z4]);
}

extern "C" void kernel_launch(void* const* d_in, const int* in_sizes, int n_in,
                              void* d_out, int out_size, void* d_ws, size_t ws_size,
                              hipStream_t stream) {
    const float* msa   = (const float*)d_in[0];
    const float* nw    = (const float*)d_in[1];
    const float* nb    = (const float*)d_in[2];
    const float* w_ab  = (const float*)d_in[3];
    const float* b_ab  = (const float*)d_in[4];
    const float* w_out = (const float*)d_in[5];
    const float* b_out = (const float*)d_in[6];
    float* out = (float*)d_out;

    float* pre  = (float*)d_ws;                    // 512 KB
    float* wt_g = pre + (size_t)NRES * CZ;         // 32 KB
    float* k12  = wt_g + CM * CC;                  // 256 B

    opm_setup<<<1, 256, 0, stream>>>(nw, nb, w_ab, b_ab, wt_g, k12);
    opm_compute<<<NRES / 2, 256, 0, stream>>>(msa, wt_g, k12, w_out, b_out, pre);
    opm_bcast<<<NRES * 8, 256, 0, stream>>>(pre, out);
}

// Round 6
// 825.159 us; speedup vs baseline: 1.0015x; 1.0015x over previous
//
#include <hip/hip_runtime.h>

#define NSEQ 256
#define NRES 1024
#define CM   256
#define CC   32
#define CZ   128
#define EPS  1e-5f
#define MCH  16            // m-chunk size (floats)
#define XPAD 20            // row stride: 20*i mod 32 hits 8 distinct 4-bank groups

typedef float f4v __attribute__((ext_vector_type(4)));

// ===================== Kernel S: precompute wt[m][c], K1, K2 =====================
__global__ void opm_setup(const float* __restrict__ nw,
                          const float* __restrict__ nb,
                          const float* __restrict__ w_ab,
                          const float* __restrict__ b_ab,
                          float* __restrict__ wt_g,
                          float* __restrict__ k12)
{
    __shared__ float wls[CM * CC];
    const int t = threadIdx.x;          // 256 threads, t == m
    const float nwm = nw[t];
    #pragma unroll
    for (int c = 0; c < CC; ++c)
        wls[t * CC + c] = nwm * w_ab[c * CM + t];
    __syncthreads();
    for (int i = t; i < CM * CC; i += 256) wt_g[i] = wls[i];
    if (t < CC) {
        float k1 = 0.f, k2 = 0.f;
        for (int m = 0; m < CM; ++m) {
            k1 += wls[m * CC + t];
            k2 = fmaf(nb[m], w_ab[t * CM + m], k2);
        }
        k12[t]      = k1;
        k12[CC + t] = k2 + b_ab[t];
    }
}

// ===================== K1: LN + projection, s-major (contiguous slabs) =====================
// Block = (s, 256-row r-slab): reads a CONTIGUOUS 256 KB region of msa
// (row r at s*NRES*CM + r*CM; rows 1 KB apart, slab contiguous) -> DRAM
// streaming instead of 1-MB-strided scatter. Writes a[s][r][c] (32 MB ws),
// 1 KB contiguous per wave-instr. Geometry/bank patterns copied verbatim
// from the round-3/4 audited kernel (SQ_LDS_BANK_CONFLICT == 0), with the
// old "s" axis now the local r-row axis.
__launch_bounds__(256, 3)
__global__ void opm_lnproj(const float* __restrict__ msa,
                           const float* __restrict__ wt_g,
                           const float* __restrict__ k12,
                           float* __restrict__ a_ws)
{
    __shared__ float wt[CM * CC];        // 32 KB
    __shared__ float xs[256 * XPAD];     // 20 KB; post-G: mu [0..255], rstd [256..511]

    const int tid = threadIdx.x;
    const int s   = blockIdx.x >> 2;
    const int r0  = (blockIdx.x & 3) << 8;

    // staging identity
    const int sc4 = tid & 3;             // f4 slot in 16-float window
    const int sg4 = tid >> 2;            // 0..63; rows sg4+64k
    // compute identity
    const int sc8 = tid & 7;
    const int sg8 = tid >> 3;            // 0..31; rows sg8+32j
    const int c0  = sc8 << 2;

    const float* xr = msa + ((size_t)s * NRES + r0) * CM + (sc4 << 2);

    // stage wt[m][c] (visible at first in-loop barrier pair)
    #pragma unroll
    for (int k = 0; k < 8; ++k) {
        const int i = (tid + (k << 8)) << 2;
        *(float4*)&wt[i] = *(const float4*)&wt_g[i];
    }

    float G[8][4];
    #pragma unroll
    for (int j = 0; j < 8; ++j) {
        G[j][0] = 0.f; G[j][1] = 0.f; G[j][2] = 0.f; G[j][3] = 0.f;
    }
    float psum[4], pssq[4];
    #pragma unroll
    for (int k = 0; k < 4; ++k) { psum[k] = 0.f; pssq[k] = 0.f; }

    // prologue: prefetch chunk 0 (4 lanes x 16 B = 64 B contiguous per row)
    float4 pf[4];
    #pragma unroll
    for (int k = 0; k < 4; ++k)
        pf[k] = *(const float4*)(xr + (size_t)(sg4 + (k << 6)) * CM);

    for (int mb = 0; mb < CM; mb += MCH) {
        __syncthreads();   // previous chunk's readers done
        #pragma unroll
        for (int k = 0; k < 4; ++k) {
            *(float4*)&xs[(sg4 + (k << 6)) * XPAD + (sc4 << 2)] = pf[k];
            psum[k] += (pf[k].x + pf[k].y) + (pf[k].z + pf[k].w);
            pssq[k]  = fmaf(pf[k].x, pf[k].x, fmaf(pf[k].y, pf[k].y,
                       fmaf(pf[k].z, pf[k].z, fmaf(pf[k].w, pf[k].w, pssq[k]))));
        }
        __syncthreads();   // chunk (and, first time, wt) visible
        if (mb + MCH < CM) {
            #pragma unroll
            for (int k = 0; k < 4; ++k)
                pf[k] = *(const float4*)(xr + (size_t)(sg4 + (k << 6)) * CM + (mb + MCH));
        }
        #pragma unroll
        for (int mm = 0; mm < MCH; mm += 4) {
            const float4 w0 = *(const float4*)&wt[(mb + mm + 0) * CC + c0];
            const float4 w1 = *(const float4*)&wt[(mb + mm + 1) * CC + c0];
            const float4 w2 = *(const float4*)&wt[(mb + mm + 2) * CC + c0];
            const float4 w3 = *(const float4*)&wt[(mb + mm + 3) * CC + c0];
            #pragma unroll
            for (int j = 0; j < 8; ++j) {
                const float4 x4 = *(const float4*)&xs[(sg8 + (j << 5)) * XPAD + mm];
                G[j][0] = fmaf(x4.x, w0.x, fmaf(x4.y, w1.x, fmaf(x4.z, w2.x, fmaf(x4.w, w3.x, G[j][0]))));
                G[j][1] = fmaf(x4.x, w0.y, fmaf(x4.y, w1.y, fmaf(x4.z, w2.y, fmaf(x4.w, w3.y, G[j][1]))));
                G[j][2] = fmaf(x4.x, w0.z, fmaf(x4.y, w1.z, fmaf(x4.z, w2.z, fmaf(x4.w, w3.z, G[j][2]))));
                G[j][3] = fmaf(x4.x, w0.w, fmaf(x4.y, w1.w, fmaf(x4.z, w2.w, fmaf(x4.w, w3.w, G[j][3]))));
            }
        }
    }
    __syncthreads();   // (A) all chunk + wt reads done

    // ---- stats: reduce over the 4 sc4-lanes, publish mu/rstd into xs[0..511] ----
    #pragma unroll
    for (int k = 0; k < 4; ++k) {
        float s1 = psum[k], s2 = pssq[k];
        s1 += __shfl_xor(s1, 1); s1 += __shfl_xor(s1, 2);
        s2 += __shfl_xor(s2, 1); s2 += __shfl_xor(s2, 2);
        if (sc4 == 0) {
            const int row = sg4 + (k << 6);
            const float mu  = s1 * (1.f / CM);
            const float var = s2 * (1.f / CM) - mu * mu;
            xs[row]       = mu;
            xs[256 + row] = 1.f / sqrtf(var + EPS);
        }
    }
    __syncthreads();   // (B) mu/rstd visible

    // ---- finalize a -> global a_ws[s][r][c] (1 KB contiguous per wave-instr) ----
    {
        const float4 k1v = *(const float4*)&k12[c0];
        const float4 k2v = *(const float4*)&k12[CC + c0];
        float* ab = a_ws + ((size_t)s * NRES + r0) * CC + c0;
        #pragma unroll
        for (int j = 0; j < 8; ++j) {
            const int row = sg8 + (j << 5);
            const float mu = xs[row], rstd = xs[256 + row];
            float4 av;
            av.x = fmaf(rstd, G[j][0] - mu * k1v.x, k2v.x);
            av.y = fmaf(rstd, G[j][1] - mu * k1v.y, k2v.y);
            av.z = fmaf(rstd, G[j][2] - mu * k1v.z, k2v.z);
            av.w = fmaf(rstd, G[j][3] - mu * k1v.w, k2v.w);
            *(float4*)&ab[(size_t)row * CC] = av;
        }
    }
}

// ===================== K2: o = A^T A / NSEQ and pre[z], per residue =====================
// Block = r. Gathers a[:, r, :] (256 rows x 128 B full-line reads, stride
// 128 KB, L2/L3-resident), stores into LDS with the round-4 XOR swizzle,
// then runs the round-3/4-verified P3 (split-K(4) x 4x4) and P4.
__launch_bounds__(256, 3)
__global__ void opm_outer(const float* __restrict__ a_ws,
                          const float* __restrict__ w_out,
                          const float* __restrict__ b_out,
                          float* __restrict__ pre_out)
{
    __shared__ float axs[NSEQ * CC];     // 32 KB, XOR-swizzled f4 slots
    __shared__ float sc[4096 + 256];     // 17 KB: P3 partials/o + pre_part

    const int tid  = threadIdx.x;
    const int r    = blockIdx.x;
    const int wave = tid >> 6;

    // gather: 8 lanes = f4 slots across one row, 8 rows per wave-instr
    {
        const int slot = tid & 7;
        const int s8   = tid >> 3;       // 0..31; s = s8+32k
        #pragma unroll
        for (int k = 0; k < 8; ++k) {
            const int s_ = s8 + (k << 5);
            const float4 v = *(const float4*)&a_ws[((size_t)s_ * NRES + r) * CC + (slot << 2)];
            *(float4*)&axs[s_ * CC + ((slot ^ (s_ & 7)) << 2)] = v;
        }
    }
    __syncthreads();

    // P3: o = A^T A / NSEQ, split-K(4) x 4x4 tiles
    const int grp = wave;                // s-slice 64*grp .. +63
    const int xs_ = (tid >> 3) & 7;      // row f4-slot
    const int ys_ = tid & 7;             // col f4-slot
    float4 pr0 = {0,0,0,0}, pr1 = {0,0,0,0}, pr2 = {0,0,0,0}, pr3 = {0,0,0,0};
    #pragma unroll 4
    for (int si = 0; si < 64; ++si) {
        const int s_ = (grp << 6) + si;
        const int sw = s_ & 7;
        const float4 ax = *(const float4*)&axs[s_ * CC + ((xs_ ^ sw) << 2)];
        const float4 ay = *(const float4*)&axs[s_ * CC + ((ys_ ^ sw) << 2)];
        pr0.x = fmaf(ax.x, ay.x, pr0.x); pr0.y = fmaf(ax.x, ay.y, pr0.y);
        pr0.z = fmaf(ax.x, ay.z, pr0.z); pr0.w = fmaf(ax.x, ay.w, pr0.w);
        pr1.x = fmaf(ax.y, ay.x, pr1.x); pr1.y = fmaf(ax.y, ay.y, pr1.y);
        pr1.z = fmaf(ax.y, ay.z, pr1.z); pr1.w = fmaf(ax.y, ay.w, pr1.w);
        pr2.x = fmaf(ax.z, ay.x, pr2.x); pr2.y = fmaf(ax.z, ay.y, pr2.y);
        pr2.z = fmaf(ax.z, ay.z, pr2.z); pr2.w = fmaf(ax.z, ay.w, pr2.w);
        pr3.x = fmaf(ax.w, ay.x, pr3.x); pr3.y = fmaf(ax.w, ay.y, pr3.y);
        pr3.z = fmaf(ax.w, ay.z, pr3.z); pr3.w = fmaf(ax.w, ay.w, pr3.w);
    }
    {
        float* pb = &sc[(grp << 10) + ((xs_ << 2) * CC) + (ys_ << 2)];
        *(float4*)&pb[0 * CC] = pr0;
        *(float4*)&pb[1 * CC] = pr1;
        *(float4*)&pb[2 * CC] = pr2;
        *(float4*)&pb[3 * CC] = pr3;
    }
    __syncthreads();   // partials visible
    {   // reduce 4 partials -> o at sc[0..1023]
        const float inv_s = 1.f / NSEQ;
        float4 acc = *(const float4*)&sc[(tid << 2)];
        const float4 b1 = *(const float4*)&sc[1024 + (tid << 2)];
        const float4 b2 = *(const float4*)&sc[2048 + (tid << 2)];
        const float4 b3 = *(const float4*)&sc[3072 + (tid << 2)];
        acc.x = (acc.x + b1.x + b2.x + b3.x) * inv_s;
        acc.y = (acc.y + b1.y + b2.y + b3.y) * inv_s;
        acc.z = (acc.z + b1.z + b2.z + b3.z) * inv_s;
        acc.w = (acc.w + b1.w + b2.w + b3.w) * inv_s;
        *(float4*)&sc[tid << 2] = acc;
    }
    __syncthreads();   // o visible

    // P4: pre[z] = o . w_out[z] + b_out[z]
    {
        const int z    = tid & 127;
        const int half = tid >> 7;
        const float* wrow = w_out + (size_t)z * (CC * CC) + half * 512;
        const float* op   = &sc[half * 512];
        float po = 0.f;
        #pragma unroll 8
        for (int k = 0; k < 512; k += 4) {
            const float4 o4 = *(const float4*)&op[k];
            const float4 w4 = *(const float4*)&wrow[k];
            po = fmaf(o4.x, w4.x, fmaf(o4.y, w4.y, fmaf(o4.z, w4.z, fmaf(o4.w, w4.w, po))));
        }
        sc[4096 + (half << 7) + (z & 127)] = po;   // half 0
        if (half) sc[4096 + 128 + z] = po;         // (half<<7) already does this; keep single path
    }
    __syncthreads();
    if (tid < CZ)
        pre_out[(size_t)r * CZ + tid] = sc[4096 + tid] + sc[4096 + CZ + tid] + b_out[tid];
}

// ===================== K3: broadcast pre over 1024 rows =====================
__launch_bounds__(256, 8)
__global__ void opm_bcast(const float* __restrict__ pre,
                          float* __restrict__ out)
{
    const int bid = blockIdx.x;
    const int r   = bid >> 3;                 // 0..1023
    const int jb  = bid & 7;                  // 128-row slab within the r-plane
    const int z4  = threadIdx.x & 31;         // which float4 of the 128-float row
    const int jo  = threadIdx.x >> 5;         // 0..7

    const f4v pv = *((const f4v*)(pre + (size_t)r * CZ) + z4);
    f4v* outp = (f4v*)out + ((size_t)r * NRES + (size_t)jb * 128) * (CZ / 4);
    for (int j0 = 0; j0 < 128; j0 += 8)
        __builtin_nontemporal_store(pv, &outp[(size_t)(j0 + jo) * (CZ / 4) + z4]);
}

extern "C" void kernel_launch(void* const* d_in, const int* in_sizes, int n_in,
                              void* d_out, int out_size, void* d_ws, size_t ws_size,
                              hipStream_t stream) {
    const float* msa   = (const float*)d_in[0];
    const float* nw    = (const float*)d_in[1];
    const float* nb    = (const float*)d_in[2];
    const float* w_ab  = (const float*)d_in[3];
    const float* b_ab  = (const float*)d_in[4];
    const float* w_out = (const float*)d_in[5];
    const float* b_out = (const float*)d_in[6];
    float* out = (float*)d_out;

    float* pre  = (float*)d_ws;                    // 512 KB
    float* wt_g = pre + (size_t)NRES * CZ;         // 32 KB
    float* k12  = wt_g + CM * CC;                  // 256 B
    float* a_ws = k12 + 64;                        // 32 MB: a[s][r][c]

    opm_setup<<<1, 256, 0, stream>>>(nw, nb, w_ab, b_ab, wt_g, k12);
    opm_lnproj<<<NRES, 256, 0, stream>>>(msa, wt_g, k12, a_ws);
    opm_outer<<<NRES, 256, 0, stream>>>(a_ws, w_out, b_out, pre);
    opm_bcast<<<NRES * 8, 256, 0, stream>>>(pre, out);
}